// Round 1
// baseline (965.347 us; speedup 1.0000x reference)
//
#include <hip/hip_runtime.h>
#include <hip/hip_bf16.h>
#include <cstdint>
#include <cstddef>

#define NQH 16
#define NKH 4
#define HN 128
#define QBLK 16
#define KBLK 64
#define SCALE 0.08838834764831845f  // 1/sqrt(128)

__device__ __forceinline__ float wave_max(float v) {
#pragma unroll
  for (int off = 32; off > 0; off >>= 1) v = fmaxf(v, __shfl_xor(v, off));
  return v;
}
__device__ __forceinline__ float wave_sum(float v) {
#pragma unroll
  for (int off = 32; off > 0; off >>= 1) v += __shfl_xor(v, off);
  return v;
}

__global__ __launch_bounds__(64) void attn_fwd_f32(
    const float* __restrict__ Q, const float* __restrict__ K,
    const float* __restrict__ V, const int* __restrict__ cu,
    float* __restrict__ O, int T, int nseg) {
  const int h    = blockIdx.y;           // query head
  const int r0   = blockIdx.x * QBLK;    // first query row of this tile
  const int lane = threadIdx.x;          // 0..63
  const int kvh  = h / (NQH / NKH);      // GQA: kv head = h / rep

  __shared__ float q_lds[QBLK][HN];      // 8 KB
  __shared__ float p_lds[QBLK][KBLK];    // 4 KB

  // ---- stage Q tile into LDS, pre-scaled ----
  for (int f = lane; f < QBLK * HN / 4; f += 64) {
    const int rr = f >> 5;               // 32 float4 per row
    const int cc = (f & 31) << 2;
    const float4 v4 =
        *(const float4*)&Q[(size_t)(r0 + rr) * (NQH * HN) + (size_t)h * HN + cc];
    q_lds[rr][cc + 0] = v4.x * SCALE;
    q_lds[rr][cc + 1] = v4.y * SCALE;
    q_lds[rr][cc + 2] = v4.z * SCALE;
    q_lds[rr][cc + 3] = v4.w * SCALE;
  }
  __syncthreads();

  // ---- per-row segment start (block-diagonal causal mask) ----
  int sstart[QBLK];
#pragma unroll
  for (int r = 0; r < QBLK; ++r) {
    const int i = r0 + r;
    int st = 0;
    for (int s = 1; s < nseg; ++s) {
      const int c = cu[s];
      if (c <= i) st = c;
    }
    sstart[r] = st;
  }
  const int kstart = sstart[0];          // min start (rows are ascending)
  const int rmax   = r0 + QBLK - 1;

  float  m_r[QBLK], l_r[QBLK];
  float2 o_r[QBLK];
#pragma unroll
  for (int r = 0; r < QBLK; ++r) {
    m_r[r] = -INFINITY;
    l_r[r] = 0.f;
    o_r[r] = make_float2(0.f, 0.f);
  }

  for (int kb = kstart; kb <= rmax; kb += KBLK) {
    const int j  = kb + lane;            // this lane's key index
    const int jc = j < T ? j : T - 1;    // clamped for addressing
    const float* kp = &K[(size_t)jc * (NKH * HN) + (size_t)kvh * HN];

    // ---- phase 1: scores s[r] = dot(q_r, k_j), lane = key ----
    float s[QBLK];
#pragma unroll
    for (int r = 0; r < QBLK; ++r) s[r] = 0.f;
#pragma unroll 4
    for (int d4 = 0; d4 < HN / 4; ++d4) {
      const float4 kv = *(const float4*)&kp[d4 * 4];
#pragma unroll
      for (int r = 0; r < QBLK; ++r) {
        const float4 qv = *(const float4*)&q_lds[r][d4 * 4];
        s[r] += kv.x * qv.x + kv.y * qv.y + kv.z * qv.z + kv.w * qv.w;
      }
    }

    // ---- phase 2: online softmax update per row ----
#pragma unroll
    for (int r = 0; r < QBLK; ++r) {
      const int i = r0 + r;
      const float sv = (j >= sstart[r] && j <= i) ? s[r] : -INFINITY;
      const float cmax = wave_max(sv);
      float p = 0.f;
      if (cmax != -INFINITY) {           // wave-uniform branch
        const float mnew = fmaxf(m_r[r], cmax);
        const float corr = __expf(m_r[r] - mnew);  // exp(-inf)=0 first time
        p = __expf(sv - mnew);                     // masked lanes -> 0
        const float ps = wave_sum(p);
        l_r[r] = l_r[r] * corr + ps;
        m_r[r] = mnew;
        o_r[r].x *= corr;
        o_r[r].y *= corr;
      }
      p_lds[r][lane] = p;
    }
    __syncthreads();

    // ---- phase 3: O += P * V, lane = dim pair (2*lane, 2*lane+1) ----
#pragma unroll 4
    for (int j4 = 0; j4 < KBLK / 4; ++j4) {
      if (kb + j4 * 4 > rmax) break;     // remaining p are all zero
      float2 vv[4];
#pragma unroll
      for (int c = 0; c < 4; ++c) {
        int kj = kb + j4 * 4 + c;
        kj = kj < T ? kj : T - 1;
        vv[c] = *(const float2*)&V[(size_t)kj * (NKH * HN) +
                                   (size_t)kvh * HN + 2 * lane];
      }
#pragma unroll
      for (int r = 0; r < QBLK; ++r) {
        const float4 pv = *(const float4*)&p_lds[r][j4 * 4];
        o_r[r].x += pv.x * vv[0].x; o_r[r].y += pv.x * vv[0].y;
        o_r[r].x += pv.y * vv[1].x; o_r[r].y += pv.y * vv[1].y;
        o_r[r].x += pv.z * vv[2].x; o_r[r].y += pv.z * vv[2].y;
        o_r[r].x += pv.w * vv[3].x; o_r[r].y += pv.w * vv[3].y;
      }
    }
    __syncthreads();
  }

  // ---- epilogue: normalize and store ----
#pragma unroll
  for (int r = 0; r < QBLK; ++r) {
    const float inv = 1.0f / l_r[r];
    float2 res = make_float2(o_r[r].x * inv, o_r[r].y * inv);
    *(float2*)&O[(size_t)(r0 + r) * (NQH * HN) + (size_t)h * HN + 2 * lane] = res;
  }
}

extern "C" void kernel_launch(void* const* d_in, const int* in_sizes, int n_in,
                              void* d_out, int out_size, void* d_ws, size_t ws_size,
                              hipStream_t stream) {
  const float* Q  = (const float*)d_in[0];
  const float* K  = (const float*)d_in[1];
  const float* V  = (const float*)d_in[2];
  const int*   cu = (const int*)d_in[3];
  float*       O  = (float*)d_out;

  const int T    = in_sizes[0] / (NQH * HN);   // 4096
  const int nseg = in_sizes[3] - 1;            // 4

  dim3 grid(T / QBLK, NQH);
  attn_fwd_f32<<<grid, 64, 0, stream>>>(Q, K, V, cu, O, T, nseg);
}

// Round 2
// 190.863 us; speedup vs baseline: 5.0578x; 5.0578x over previous
//
#include <hip/hip_runtime.h>
#include <hip/hip_bf16.h>
#include <cstdint>
#include <cstddef>

#define NQH 16
#define NKH 4
#define HN 128
#define QBLK 64
#define KBLK 64
#define SCALE 0.08838834764831845f  // 1/sqrt(128)

typedef __bf16 bf16x8 __attribute__((ext_vector_type(8)));
typedef float f32x4 __attribute__((ext_vector_type(4)));

#define KSTRIDE 136  // 128 + 8 pad -> row stride 272B, banks advance 4/row
#define VSTRIDE 72   // 64 + 8 pad  -> row stride 144B
#define PSTRIDE 72

__global__ __launch_bounds__(256, 2) void attn_mfma(
    const float* __restrict__ Q, const float* __restrict__ K,
    const float* __restrict__ V, const int* __restrict__ cu,
    float* __restrict__ O, int T, int nseg) {
  const int h   = blockIdx.y;
  const int r0  = blockIdx.x * QBLK;
  const int kvh = h / (NQH / NKH);
  const int tid = threadIdx.x;
  const int w   = tid >> 6;    // wave 0..3, owns rows r0+w*16..+15
  const int lane = tid & 63;
  const int ln  = lane & 15;   // 0..15
  const int hi  = lane >> 4;   // 0..3

  __shared__ __bf16 K_lds[KBLK][KSTRIDE];  // 17 KB, row-major (key, dim)
  __shared__ __bf16 V_T[HN][VSTRIDE];      // 18 KB, transposed (dim, key)
  __shared__ __bf16 P_lds[QBLK][PSTRIDE];  // 9 KB

  // ---- Q fragments in registers (A-layout), pre-scaled ----
  bf16x8 qf[4];
  {
    const float* qp = &Q[(size_t)(r0 + w * 16 + ln) * (NQH * HN) + h * HN];
#pragma unroll
    for (int kc = 0; kc < 4; ++kc) {
      const float* p = qp + kc * 32 + hi * 8;
      float4 a = *(const float4*)p;
      float4 b = *(const float4*)(p + 4);
      bf16x8 f;
      f[0] = (__bf16)(a.x * SCALE); f[1] = (__bf16)(a.y * SCALE);
      f[2] = (__bf16)(a.z * SCALE); f[3] = (__bf16)(a.w * SCALE);
      f[4] = (__bf16)(b.x * SCALE); f[5] = (__bf16)(b.y * SCALE);
      f[6] = (__bf16)(b.z * SCALE); f[7] = (__bf16)(b.w * SCALE);
      qf[kc] = f;
    }
  }

  // ---- per-row segment starts (block-diagonal causal mask) ----
  int row_[4], sst[4];
#pragma unroll
  for (int i = 0; i < 4; ++i) { row_[i] = r0 + w * 16 + hi * 4 + i; sst[i] = 0; }
  int st0 = 0;
  for (int s = 1; s < nseg; ++s) {
    const int c = cu[s];
    if (c <= r0) st0 = c;
#pragma unroll
    for (int i = 0; i < 4; ++i)
      if (c <= row_[i]) sst[i] = c;
  }
  const int kstart = st0 & ~(KBLK - 1);

  float m_[4], l_[4];
  f32x4 o_acc[8];
#pragma unroll
  for (int i = 0; i < 4; ++i) { m_[i] = -1e30f; l_[i] = 0.f; }
#pragma unroll
  for (int dt = 0; dt < 8; ++dt) o_acc[dt] = (f32x4){0.f, 0.f, 0.f, 0.f};

  for (int kb = kstart; kb <= r0 + QBLK - 1; kb += KBLK) {
    // ---- stage K (row-major, padded): 16B slots, ds_write_b128 ----
#pragma unroll
    for (int it = 0; it < 4; ++it) {
      const int sidx = tid + it * 256;        // 0..1023
      const int row = sidx >> 4, slot = sidx & 15;
      const float* src = &K[(size_t)(kb + row) * (NKH * HN) + kvh * HN + slot * 8];
      float4 a = *(const float4*)src;
      float4 b = *(const float4*)(src + 4);
      bf16x8 f;
      f[0] = (__bf16)a.x; f[1] = (__bf16)a.y; f[2] = (__bf16)a.z; f[3] = (__bf16)a.w;
      f[4] = (__bf16)b.x; f[5] = (__bf16)b.y; f[6] = (__bf16)b.z; f[7] = (__bf16)b.w;
      *(bf16x8*)&K_lds[row][slot * 8] = f;
    }
    // ---- stage V transposed: thread owns rows (j2,j2+1) x 16 dims ----
    {
      const int j2 = (tid & 31) * 2;
      const int dg = tid >> 5;  // 0..7
      const float* v0 = &V[(size_t)(kb + j2) * (NKH * HN) + kvh * HN + dg * 16];
      const float* v1 = v0 + NKH * HN;
#pragma unroll
      for (int q = 0; q < 4; ++q) {
        float4 x0 = *(const float4*)(v0 + q * 4);
        float4 x1 = *(const float4*)(v1 + q * 4);
        const float* f0 = (const float*)&x0;
        const float* f1 = (const float*)&x1;
#pragma unroll
        for (int e = 0; e < 4; ++e) {
          const int d = dg * 16 + q * 4 + e;
          union { __bf16 hh[2]; unsigned int u; } pk;
          pk.hh[0] = (__bf16)f0[e];
          pk.hh[1] = (__bf16)f1[e];
          *(unsigned int*)&V_T[d][j2] = pk.u;  // conflict-free packed b32
        }
      }
    }
    __syncthreads();

    // ---- QK^T: S[16 rows][64 keys] per wave ----
    f32x4 s[4];
#pragma unroll
    for (int c = 0; c < 4; ++c) s[c] = (f32x4){0.f, 0.f, 0.f, 0.f};
#pragma unroll
    for (int kc = 0; kc < 4; ++kc) {
#pragma unroll
      for (int c = 0; c < 4; ++c) {
        bf16x8 bf = *(const bf16x8*)&K_lds[c * 16 + ln][kc * 32 + hi * 8];
        s[c] = __builtin_amdgcn_mfma_f32_16x16x32_bf16(qf[kc], bf, s[c], 0, 0, 0);
      }
    }

    // ---- online softmax (row r lives in lanes with hi=r/4, reg r%4) ----
#pragma unroll
    for (int i = 0; i < 4; ++i) {
      bool valid[4];
      float mloc = -1e30f;
#pragma unroll
      for (int c = 0; c < 4; ++c) {
        const int key = kb + c * 16 + ln;
        valid[c] = (key >= sst[i]) && (key <= row_[i]);
        mloc = fmaxf(mloc, valid[c] ? s[c][i] : -1e30f);
      }
#pragma unroll
      for (int off = 1; off < 16; off <<= 1)
        mloc = fmaxf(mloc, __shfl_xor(mloc, off));
      const float mnew = fmaxf(m_[i], mloc);
      const float corr = __expf(m_[i] - mnew);  // -1e30 path underflows to 0
      float psum = 0.f;
      float pv[4];
#pragma unroll
      for (int c = 0; c < 4; ++c) {
        pv[c] = valid[c] ? __expf(s[c][i] - mnew) : 0.f;
        psum += pv[c];
      }
#pragma unroll
      for (int off = 1; off < 16; off <<= 1) psum += __shfl_xor(psum, off);
      l_[i] = l_[i] * corr + psum;
      m_[i] = mnew;
#pragma unroll
      for (int dt = 0; dt < 8; ++dt) o_acc[dt][i] *= corr;
#pragma unroll
      for (int c = 0; c < 4; ++c)
        P_lds[w * 16 + hi * 4 + i][c * 16 + ln] = (__bf16)pv[c];
    }

    // ---- PV: O[16 rows][128 dims] += P * V (wave-private P rows) ----
#pragma unroll
    for (int ch = 0; ch < 2; ++ch) {
      bf16x8 pa = *(const bf16x8*)&P_lds[w * 16 + ln][ch * 32 + hi * 8];
#pragma unroll
      for (int dt = 0; dt < 8; ++dt) {
        bf16x8 vb = *(const bf16x8*)&V_T[dt * 16 + ln][ch * 32 + hi * 8];
        o_acc[dt] = __builtin_amdgcn_mfma_f32_16x16x32_bf16(pa, vb, o_acc[dt], 0, 0, 0);
      }
    }
    __syncthreads();
  }

  // ---- epilogue ----
#pragma unroll
  for (int i = 0; i < 4; ++i) {
    const float inv = 1.0f / l_[i];
    float* op = &O[(size_t)row_[i] * (NQH * HN) + h * HN];
#pragma unroll
    for (int dt = 0; dt < 8; ++dt) op[dt * 16 + ln] = o_acc[dt][i] * inv;
  }
}

extern "C" void kernel_launch(void* const* d_in, const int* in_sizes, int n_in,
                              void* d_out, int out_size, void* d_ws, size_t ws_size,
                              hipStream_t stream) {
  const float* Q  = (const float*)d_in[0];
  const float* K  = (const float*)d_in[1];
  const float* V  = (const float*)d_in[2];
  const int*   cu = (const int*)d_in[3];
  float*       O  = (float*)d_out;

  const int T    = in_sizes[0] / (NQH * HN);  // 4096
  const int nseg = in_sizes[3] - 1;           // 4

  dim3 grid(T / QBLK, NQH);
  attn_mfma<<<grid, 256, 0, stream>>>(Q, K, V, cu, O, T, nseg);
}

// Round 4
// 147.112 us; speedup vs baseline: 6.5620x; 1.2974x over previous
//
#include <hip/hip_runtime.h>
#include <hip/hip_bf16.h>
#include <cstdint>
#include <cstddef>

#define NQH 16
#define NKH 4
#define HN 128
#define QBLK 64
#define KBLK 64
// SCALE * log2(e): softmax computed in exp2 domain
#define QSCALE 0.12751589542585458f

typedef __bf16 bf16x8 __attribute__((ext_vector_type(8)));
typedef float f32x4 __attribute__((ext_vector_type(4)));

__device__ __forceinline__ void gload16(const void* g, void* l) {
  __builtin_amdgcn_global_load_lds(
      (const __attribute__((address_space(1))) void*)g,
      (__attribute__((address_space(3))) void*)l, 16, 0, 0);
}

// ---- pre-kernel A: K f32 [T][4][128] -> Kb bf16 [4][T][128] ----
__global__ __launch_bounds__(256) void cvt_k(const float* __restrict__ K,
                                             __bf16* __restrict__ Kb, int T) {
  const size_t idx8 = ((size_t)blockIdx.x * 256 + threadIdx.x) * 8;
  const int d = (int)(idx8 & 127);
  const int kvh = (int)((idx8 >> 7) & 3);
  const size_t t = idx8 >> 9;
  float4 a = *(const float4*)&K[idx8];
  float4 b = *(const float4*)&K[idx8 + 4];
  bf16x8 f;
  f[0] = (__bf16)a.x; f[1] = (__bf16)a.y; f[2] = (__bf16)a.z; f[3] = (__bf16)a.w;
  f[4] = (__bf16)b.x; f[5] = (__bf16)b.y; f[6] = (__bf16)b.z; f[7] = (__bf16)b.w;
  *(bf16x8*)&Kb[(size_t)kvh * T * HN + t * HN + d] = f;
}

// ---- pre-kernel B: V f32 [T][4][128] -> Vb bf16 [4][128][T] (transposed) ----
__global__ __launch_bounds__(128) void cvt_v(const float* __restrict__ V,
                                             __bf16* __restrict__ Vb, int T) {
  const int d = threadIdx.x;           // 0..127
  const int t0 = blockIdx.x * 8;
  const int kvh = blockIdx.y;
  bf16x8 f;
#pragma unroll
  for (int i = 0; i < 8; ++i)
    f[i] = (__bf16)V[(size_t)(t0 + i) * (NKH * HN) + kvh * HN + d];
  *(bf16x8*)&Vb[(size_t)kvh * HN * T + (size_t)d * T + t0] = f;
}

// ---- main attention kernel ----
__global__ __launch_bounds__(256, 3) void attn_mfma2(
    const float* __restrict__ Q, const __bf16* __restrict__ Kb,
    const __bf16* __restrict__ Vb, const int* __restrict__ cu,
    float* __restrict__ O, int T, int nseg) {
  const int h = blockIdx.y;
  const int r0 = blockIdx.x * QBLK;
  const int kvh = h >> 2;
  const int tid = threadIdx.x;
  const int w = tid >> 6, lane = tid & 63;
  const int ln = lane & 15, hi = lane >> 4;

  __shared__ __bf16 K_lds[KBLK * HN];   // 16 KB, swizzled image [key][dim]
  __shared__ __bf16 V_lds[HN * KBLK];   // 16 KB, swizzled image [dim][key]
  __shared__ __bf16 P_lds[QBLK][80];    // 10 KB, per-wave-private rows

  const __bf16* KbH = Kb + (size_t)kvh * T * HN;
  const __bf16* VbH = Vb + (size_t)kvh * HN * T;

  // ---- Q fragments (A-layout), scaled by 1/sqrt(d)*log2(e) ----
  bf16x8 qf[4];
  {
    const float* qp = &Q[(size_t)(r0 + w * 16 + ln) * (NQH * HN) + h * HN];
#pragma unroll
    for (int kc = 0; kc < 4; ++kc) {
      float4 a = *(const float4*)(qp + kc * 32 + hi * 8);
      float4 b = *(const float4*)(qp + kc * 32 + hi * 8 + 4);
      bf16x8 f;
      f[0] = (__bf16)(a.x * QSCALE); f[1] = (__bf16)(a.y * QSCALE);
      f[2] = (__bf16)(a.z * QSCALE); f[3] = (__bf16)(a.w * QSCALE);
      f[4] = (__bf16)(b.x * QSCALE); f[5] = (__bf16)(b.y * QSCALE);
      f[6] = (__bf16)(b.z * QSCALE); f[7] = (__bf16)(b.w * QSCALE);
      qf[kc] = f;
    }
  }

  // ---- per-row segment starts ----
  int row_[4], sst[4];
#pragma unroll
  for (int i = 0; i < 4; ++i) { row_[i] = r0 + w * 16 + hi * 4 + i; sst[i] = 0; }
  int st0 = 0;
  for (int s = 1; s < nseg; ++s) {
    const int c = cu[s];
    if (c <= r0) st0 = c;
#pragma unroll
    for (int i = 0; i < 4; ++i)
      if (c <= row_[i]) sst[i] = c;
  }
  const int kstart = st0 & ~(KBLK - 1);

  float m_[4], l_[4];
  f32x4 acc[8];
#pragma unroll
  for (int i = 0; i < 4; ++i) { m_[i] = -1e30f; l_[i] = 0.f; }
#pragma unroll
  for (int dt = 0; dt < 8; ++dt) acc[dt] = (f32x4){0.f, 0.f, 0.f, 0.f};

  // ---- staging address components (loop-invariant) ----
  // K round j: LDS byte = j*4096 + w*1024 + lane*16 -> row r = j*16 + w*4 + hi,
  // slot = ln; swizzled source slot = ln ^ (r&7), (r&7) = (w*4+hi)&7.
  const int krow = w * 4 + hi;
  const int kcol = ((ln ^ (krow & 7)) << 3);
  // V round j: row d = j*32 + w*8 + (lane>>3), slot = lane&7;
  // (d&7) = (lane>>3)&7.
  const int vrow = w * 8 + (lane >> 3);
  const int vcol = (((lane & 7) ^ ((lane >> 3) & 7)) << 3);
  char* ldsK = (char*)K_lds + w * 1024 + (size_t)(lane & 63) * 16;
  char* ldsV = (char*)V_lds + w * 1024 + (size_t)(lane & 63) * 16;

  for (int kb = kstart; kb < r0 + QBLK; kb += KBLK) {
    // ---- DMA stage K and V tiles (8 x 16B per thread) ----
#pragma unroll
    for (int j = 0; j < 4; ++j)
      gload16(KbH + (size_t)(kb + j * 16 + krow) * HN + kcol, ldsK + j * 4096);
#pragma unroll
    for (int j = 0; j < 4; ++j)
      gload16(VbH + (size_t)(vrow + j * 32) * T + kb + vcol, ldsV + j * 4096);
    __syncthreads();  // drains vmcnt(0): tiles ready

    // ---- QK^T: S[16 rows][64 keys] per wave ----
    f32x4 s[4];
#pragma unroll
    for (int c = 0; c < 4; ++c) s[c] = (f32x4){0.f, 0.f, 0.f, 0.f};
#pragma unroll
    for (int kc = 0; kc < 4; ++kc) {
#pragma unroll
      for (int c = 0; c < 4; ++c) {
        const int row = c * 16 + ln;
        const bf16x8 bf = *(const bf16x8*)((const char*)K_lds + row * 256 +
                                           (((kc * 4 + hi) ^ (row & 7)) << 4));
        s[c] = __builtin_amdgcn_mfma_f32_16x16x32_bf16(qf[kc], bf, s[c], 0, 0, 0);
      }
    }

    // ---- online softmax (exp2 domain, defer-max THR=8) ----
    float mloc[4];
#pragma unroll
    for (int i = 0; i < 4; ++i) {
      float mm = -1e30f;
#pragma unroll
      for (int c = 0; c < 4; ++c) {
        const int key = kb + c * 16 + ln;
        const bool valid = (key >= sst[i]) & (key <= row_[i]);
        mm = fmaxf(mm, valid ? s[c][i] : -1e30f);
      }
#pragma unroll
      for (int off = 1; off < 16; off <<= 1) mm = fmaxf(mm, __shfl_xor(mm, off));
      mloc[i] = mm;
    }
    bool need = false;
#pragma unroll
    for (int i = 0; i < 4; ++i) need |= (mloc[i] > m_[i] + 8.0f);
    if (__any(need)) {
#pragma unroll
      for (int i = 0; i < 4; ++i) {
        const float mnew = fmaxf(m_[i], mloc[i]);
        const float corr = exp2f(m_[i] - mnew);
        m_[i] = mnew;
        l_[i] *= corr;
#pragma unroll
        for (int dt = 0; dt < 8; ++dt) acc[dt][i] *= corr;
      }
    }
#pragma unroll
    for (int i = 0; i < 4; ++i) {
      float ps = 0.f;
#pragma unroll
      for (int c = 0; c < 4; ++c) {
        const int key = kb + c * 16 + ln;
        const bool valid = (key >= sst[i]) & (key <= row_[i]);
        const float p = valid ? exp2f(s[c][i] - m_[i]) : 0.f;
        ps += p;
        P_lds[w * 16 + hi * 4 + i][c * 16 + ln] = (__bf16)p;
      }
#pragma unroll
      for (int off = 1; off < 16; off <<= 1) ps += __shfl_xor(ps, off);
      l_[i] += ps;
    }

    // ---- PV: O[16 rows][128 dims] += P * V^T (P is wave-private: no barrier) ----
#pragma unroll
    for (int ch = 0; ch < 2; ++ch) {
      const bf16x8 pa = *(const bf16x8*)&P_lds[w * 16 + ln][ch * 32 + hi * 8];
#pragma unroll
      for (int dt = 0; dt < 8; ++dt) {
        const int vr = dt * 16 + ln;
        const bf16x8 vb = *(const bf16x8*)((const char*)V_lds + vr * 128 +
                                           (((ch * 4 + hi) ^ (vr & 7)) << 4));
        acc[dt] = __builtin_amdgcn_mfma_f32_16x16x32_bf16(pa, vb, acc[dt], 0, 0, 0);
      }
    }
    __syncthreads();  // all waves done reading before next stage overwrites
  }

  // ---- epilogue ----
#pragma unroll
  for (int i = 0; i < 4; ++i) {
    const float inv = 1.0f / l_[i];
    float* op = &O[(size_t)row_[i] * (NQH * HN) + h * HN];
#pragma unroll
    for (int dt = 0; dt < 8; ++dt) op[dt * 16 + ln] = acc[dt][i] * inv;
  }
}

extern "C" void kernel_launch(void* const* d_in, const int* in_sizes, int n_in,
                              void* d_out, int out_size, void* d_ws, size_t ws_size,
                              hipStream_t stream) {
  const float* Q = (const float*)d_in[0];
  const float* K = (const float*)d_in[1];
  const float* V = (const float*)d_in[2];
  const int* cu = (const int*)d_in[3];
  float* O = (float*)d_out;

  const int T = in_sizes[0] / (NQH * HN);  // 4096
  const int nseg = in_sizes[3] - 1;        // 4

  const size_t need = (size_t)2 * NKH * T * HN * sizeof(__bf16);  // 8 MB
  if (ws_size < need) return;  // fail loudly (validation) rather than corrupt

  __bf16* Kb = (__bf16*)d_ws;                          // 4 MB
  __bf16* Vb = (__bf16*)d_ws + (size_t)NKH * T * HN;   // 4 MB

  const int nelem = T * NKH * HN;
  cvt_k<<<nelem / 8 / 256, 256, 0, stream>>>(K, Kb, T);
  cvt_v<<<dim3(T / 8, NKH), 128, 0, stream>>>(V, Vb, T);

  dim3 grid(T / QBLK, NQH);
  attn_mfma2<<<grid, 256, 0, stream>>>(Q, Kb, Vb, cu, O, T, nseg);
}